// Round 1
// baseline (869.601 us; speedup 1.0000x reference)
//
#include <hip/hip_runtime.h>
#include <hip/hip_bf16.h>
#include <math.h>

#define BB 8
#define CC 64
#define NN 500
#define TT 12
#define HH 4
#define FF 64
#define CT (CC*TT)      // 768
#define HF (HH*FF)      // 256
#define NROWS (BB*HH*TT*NN)  // 192000

// ---------------------------------------------------------------------------
// K0: build CSR of mask = (adj + I) > 0.  One block, 512 threads.
// ---------------------------------------------------------------------------
__global__ __launch_bounds__(512) void k0_csr(const float* __restrict__ adj,
                                              int* __restrict__ row_ptr,
                                              int* __restrict__ col_idx) {
    __shared__ int scan[512];
    int n = threadIdx.x;
    int d = 0;
    if (n < NN) {
        for (int m = 0; m < NN; ++m) {
            float v = adj[n*NN + m];
            if (v > 0.f || m == n) d++;
        }
    }
    int val = d;
    scan[n] = val;
    __syncthreads();
    for (int off = 1; off < 512; off <<= 1) {
        int add = (n >= off) ? scan[n - off] : 0;
        __syncthreads();
        val += add;
        scan[n] = val;
        __syncthreads();
    }
    if (n < NN) {
        int ptr = val - d;              // exclusive prefix
        for (int m = 0; m < NN; ++m) {
            float v = adj[n*NN + m];
            if (v > 0.f || m == n) col_idx[ptr++] = m;
        }
        row_ptr[n + 1] = val;
        if (n == 0) row_ptr[0] = 0;
    }
}

// ---------------------------------------------------------------------------
// K1: prep. p1[h,c] = sum_f W[h,c,f]*a1[h,f]; p2 same with a2.
//     WmT[c*64+o] = Wm[o*192+c].
// ---------------------------------------------------------------------------
__global__ __launch_bounds__(256) void k1_prep(const float* __restrict__ W,
                                               const float* __restrict__ a1,
                                               const float* __restrict__ a2,
                                               const float* __restrict__ Wm,
                                               float* __restrict__ p1,
                                               float* __restrict__ p2,
                                               float* __restrict__ WmT) {
    int idx = blockIdx.x * 256 + threadIdx.x;
    if (idx < HH*CC) {
        int h = idx / CC, c = idx % CC;
        float s1 = 0.f, s2 = 0.f;
        for (int f = 0; f < FF; ++f) {
            float w = W[(h*CC + c)*FF + f];
            s1 += w * a1[h*FF + f];
            s2 += w * a2[h*FF + f];
        }
        p1[idx] = s1; p2[idx] = s2;
    }
    int j = idx - HH*CC;
    if (j >= 0 && j < 3*CC*CC) {   // 192*64
        int c = j >> 6, o = j & 63;
        WmT[j] = Wm[o*(3*CC) + c];
    }
}

// ---------------------------------------------------------------------------
// K2: Wh[b,h,t,n,f] = sum_c h[b,c,n,t] * W[h,c,f]   (+ e1/e2 via p1/p2)
// One wave per (b,n); lane: h = lane>>4, fb = lane&15, covers f = fb+16q.
// hin_layout: 0 = [B,C,N,T] (x), 1 = [(b*N+n)*768 + c*12 + t] (h buffers)
// ---------------------------------------------------------------------------
__global__ __launch_bounds__(256) void k2_wh_e(const float* __restrict__ hin,
                                               int hin_layout,
                                               const float* __restrict__ W,
                                               const float* __restrict__ p1,
                                               const float* __restrict__ p2,
                                               float* __restrict__ Wh,
                                               float* __restrict__ e1,
                                               float* __restrict__ e2) {
    __shared__ float hL[4][CT];
    int wid  = threadIdx.x >> 6;
    int lane = threadIdx.x & 63;
    int gidx = blockIdx.x * 4 + wid;       // (b, n)
    int b = gidx / NN, n = gidx % NN;

    if (hin_layout == 0) {
        for (int i = lane; i < CT; i += 64) {
            int c = i / TT, t = i % TT;
            hL[wid][i] = hin[((b*CC + c)*NN + n)*TT + t];
        }
    } else {
        const float* src = hin + (size_t)(b*NN + n) * CT;
        for (int i = lane; i < CT; i += 64) hL[wid][i] = src[i];
    }
    __syncthreads();

    const float* hLw = hL[wid];
    int h  = lane >> 4;
    int fb = lane & 15;

    float acc[4][TT];
    #pragma unroll
    for (int q = 0; q < 4; ++q)
        #pragma unroll
        for (int t = 0; t < TT; ++t) acc[q][t] = 0.f;

    for (int c = 0; c < CC; ++c) {
        float w0 = W[(h*CC + c)*FF + fb];
        float w1 = W[(h*CC + c)*FF + fb + 16];
        float w2 = W[(h*CC + c)*FF + fb + 32];
        float w3 = W[(h*CC + c)*FF + fb + 48];
        #pragma unroll
        for (int t = 0; t < TT; ++t) {
            float v = hLw[c*TT + t];
            acc[0][t] += v * w0;
            acc[1][t] += v * w1;
            acc[2][t] += v * w2;
            acc[3][t] += v * w3;
        }
    }
    #pragma unroll
    for (int q = 0; q < 4; ++q) {
        int f = fb + 16*q;
        #pragma unroll
        for (int t = 0; t < TT; ++t) {
            Wh[(size_t)(((b*HH + h)*TT + t)*NN + n)*FF + f] = acc[q][t];
        }
    }

    // e1/e2: lane -> (h2 = lane>>4, t2 = lane&15 if < 12)
    int t2 = lane & 15;
    if (t2 < TT) {
        int h2 = lane >> 4;
        float s1 = 0.f, s2 = 0.f;
        for (int c = 0; c < CC; ++c) {
            float v = hLw[c*TT + t2];
            s1 += v * p1[h2*CC + c];
            s2 += v * p2[h2*CC + c];
        }
        int idx = ((b*HH + h2)*TT + t2)*NN + n;
        e1[idx] = s1;
        e2[idx] = s2;
    }
}

// ---------------------------------------------------------------------------
// K3: sparse attention + PV + elu.  One wave per row r = bht*N + n.
// scores = leakyrelu(e1[n] + e2[m]); softmax over edges (shift-free: scores
// are O(1), exp cannot overflow; softmax is shift-invariant so this matches
// the reference up to fp rounding).
// ---------------------------------------------------------------------------
__global__ __launch_bounds__(256) void k3_attn(const float* __restrict__ Wh,
                                               const float* __restrict__ e1,
                                               const float* __restrict__ e2,
                                               const int* __restrict__ row_ptr,
                                               const int* __restrict__ col_idx,
                                               float* __restrict__ hpr) {
    __shared__ float exw[4][512];
    __shared__ int   colw[4][512];
    int wid  = threadIdx.x >> 6;
    int lane = threadIdx.x & 63;
    int r    = blockIdx.x * 4 + wid;       // [0, NROWS)
    int n    = r % NN;
    int bht  = r / NN;

    int start = row_ptr[n], end = row_ptr[n + 1];
    int deg = end - start;
    const float* e2p = e2 + (size_t)bht * NN;
    float e1v = e1[(size_t)bht * NN + n];

    float lsum = 0.f;
    for (int i = lane; i < deg; i += 64) {
        int m = col_idx[start + i];
        float s = e1v + e2p[m];
        s = s > 0.f ? s : 0.2f * s;
        float ex = expf(s);
        exw[wid][i]  = ex;
        colw[wid][i] = m;
        lsum += ex;
    }
    #pragma unroll
    for (int d = 1; d < 64; d <<= 1) lsum += __shfl_xor(lsum, d);
    __syncthreads();

    const float* Whp = Wh + (size_t)bht * NN * FF;
    float acc = 0.f;
    for (int i = 0; i < deg; ++i) {
        float ex = exw[wid][i];
        int m    = colw[wid][i];
        acc += ex * Whp[(size_t)m * FF + lane];
    }
    acc /= lsum;
    float o = acc > 0.f ? acc : expm1f(acc);
    hpr[(size_t)((size_t)bht * NN + n) * FF + lane] = o;
}

// ---------------------------------------------------------------------------
// K4: head-mix 1x1 conv + residual.
// hnext[(b*N+n)*768 + o*12 + t] = 0.05*x[b,o,n,t] + 0.95*(bg[o] +
//      sum_k hpr[b, k>>6, t, n, k&63] * Wg[o*256+k])
// One wave per (b,n); lane: ob = lane&15, tq = lane>>4; each thread does
// o in {ob, ob+16, ob+32, ob+48}, t in {tq, tq+4, tq+8}.
// ---------------------------------------------------------------------------
__global__ __launch_bounds__(256) void k4_out_res(const float* __restrict__ hpr,
                                                  const float* __restrict__ Wg,
                                                  const float* __restrict__ bg,
                                                  const float* __restrict__ x,
                                                  float* __restrict__ hnext) {
    __shared__ float pL[4][HH*TT*FF];   // 4 x 3072 floats = 48 KB
    int wid  = threadIdx.x >> 6;
    int lane = threadIdx.x & 63;
    int gidx = blockIdx.x * 4 + wid;
    int b = gidx / NN, n = gidx % NN;

    float* P = pL[wid];
    for (int ch = 0; ch < HH*TT; ++ch) {
        P[ch*64 + lane] = hpr[(size_t)((b*HH*TT + ch)*NN + n)*FF + lane];
    }
    __syncthreads();

    int ob = lane & 15;
    int tq = lane >> 4;

    float acc[4][3];
    #pragma unroll
    for (int oi = 0; oi < 4; ++oi) {
        float bgv = bg[ob + 16*oi];
        #pragma unroll
        for (int ti = 0; ti < 3; ++ti) acc[oi][ti] = bgv;
    }

    for (int k4 = 0; k4 < 64; ++k4) {
        int h  = k4 >> 4;
        int f0 = (k4 & 15) * 4;
        float4 hv[3];
        #pragma unroll
        for (int ti = 0; ti < 3; ++ti) {
            int t = tq + 4*ti;
            hv[ti] = *(const float4*)&P[(h*TT + t)*FF + f0];
        }
        #pragma unroll
        for (int oi = 0; oi < 4; ++oi) {
            int o = ob + 16*oi;
            float4 wv = *(const float4*)&Wg[o*HF + k4*4];
            #pragma unroll
            for (int ti = 0; ti < 3; ++ti) {
                acc[oi][ti] += hv[ti].x*wv.x + hv[ti].y*wv.y
                             + hv[ti].z*wv.z + hv[ti].w*wv.w;
            }
        }
    }

    float* hout = hnext + (size_t)(b*NN + n) * CT;
    #pragma unroll
    for (int oi = 0; oi < 4; ++oi) {
        int o = ob + 16*oi;
        #pragma unroll
        for (int ti = 0; ti < 3; ++ti) {
            int t = tq + 4*ti;
            float xv = x[((b*CC + o)*NN + n)*TT + t];
            hout[o*TT + t] = 0.05f * xv + 0.95f * acc[oi][ti];
        }
    }
}

// ---------------------------------------------------------------------------
// K5: final mix. out[b,o,n,t] = bm[o] + sum_{c<192} ho[c]*Wm[o,c]
// where ho = [x | h1 | h2] along channels.  One wave per (b,n).
// ---------------------------------------------------------------------------
__global__ __launch_bounds__(256) void k5_final(const float* __restrict__ x,
                                                const float* __restrict__ h1,
                                                const float* __restrict__ h2,
                                                const float* __restrict__ WmT,
                                                const float* __restrict__ bm,
                                                float* __restrict__ out) {
    __shared__ float sL[4][3][CT];      // 36 KB
    int wid  = threadIdx.x >> 6;
    int lane = threadIdx.x & 63;
    int gidx = blockIdx.x * 4 + wid;
    int b = gidx / NN, n = gidx % NN;

    float (*S)[CT] = sL[wid];
    for (int i = lane; i < CT; i += 64) {
        int c = i / TT, t = i % TT;
        S[0][i] = x[((b*CC + c)*NN + n)*TT + t];
    }
    const float* h1p = h1 + (size_t)(b*NN + n) * CT;
    const float* h2p = h2 + (size_t)(b*NN + n) * CT;
    for (int i = lane; i < CT; i += 64) {
        S[1][i] = h1p[i];
        S[2][i] = h2p[i];
    }
    __syncthreads();

    int ob = lane & 15;
    int tq = lane >> 4;

    float acc[4][3];
    #pragma unroll
    for (int oi = 0; oi < 4; ++oi) {
        float bv = bm[ob + 16*oi];
        #pragma unroll
        for (int ti = 0; ti < 3; ++ti) acc[oi][ti] = bv;
    }

    for (int c = 0; c < CC; ++c) {
        float v0[3], v1[3], v2[3];
        #pragma unroll
        for (int ti = 0; ti < 3; ++ti) {
            int t = tq + 4*ti;
            v0[ti] = S[0][c*TT + t];
            v1[ti] = S[1][c*TT + t];
            v2[ti] = S[2][c*TT + t];
        }
        #pragma unroll
        for (int oi = 0; oi < 4; ++oi) {
            int o = ob + 16*oi;
            float w0 = WmT[(c        )*64 + o];
            float w1 = WmT[(CC  + c  )*64 + o];
            float w2 = WmT[(2*CC + c )*64 + o];
            #pragma unroll
            for (int ti = 0; ti < 3; ++ti) {
                acc[oi][ti] += v0[ti]*w0 + v1[ti]*w1 + v2[ti]*w2;
            }
        }
    }

    #pragma unroll
    for (int oi = 0; oi < 4; ++oi) {
        int o = ob + 16*oi;
        #pragma unroll
        for (int ti = 0; ti < 3; ++ti) {
            int t = tq + 4*ti;
            out[((b*CC + o)*NN + n)*TT + t] = acc[oi][ti];
        }
    }
}

// ---------------------------------------------------------------------------
extern "C" void kernel_launch(void* const* d_in, const int* in_sizes, int n_in,
                              void* d_out, int out_size, void* d_ws, size_t ws_size,
                              hipStream_t stream) {
    const float* x   = (const float*)d_in[0];
    const float* adj = (const float*)d_in[1];
    const float* W   = (const float*)d_in[2];
    const float* a1  = (const float*)d_in[3];
    const float* a2  = (const float*)d_in[4];
    const float* Wg  = (const float*)d_in[5];
    const float* bg  = (const float*)d_in[6];
    const float* Wm  = (const float*)d_in[7];
    const float* bm  = (const float*)d_in[8];
    float* out = (float*)d_out;

    char* ws = (char*)d_ws;
    size_t off = 0;
    auto alloc = [&](size_t bytes) -> void* {
        void* p = ws + off;
        off += (bytes + 255) & ~(size_t)255;
        return p;
    };

    int*   row_ptr = (int*)  alloc(501 * sizeof(int));
    int*   col_idx = (int*)  alloc((size_t)NN * NN * sizeof(int));
    float* p1      = (float*)alloc(HH*CC * sizeof(float));
    float* p2      = (float*)alloc(HH*CC * sizeof(float));
    float* WmT     = (float*)alloc(3*CC*CC * sizeof(float));
    float* Wh      = (float*)alloc((size_t)NROWS * FF * sizeof(float));  // 49.15 MB
    float* hpr     = (float*)alloc((size_t)NROWS * FF * sizeof(float));  // 49.15 MB
    float* e1      = (float*)alloc((size_t)NROWS * sizeof(float));
    float* e2      = (float*)alloc((size_t)NROWS * sizeof(float));
    float* h1      = (float*)alloc((size_t)BB*NN*CT * sizeof(float));    // 12.3 MB
    float* h2      = (float*)alloc((size_t)BB*NN*CT * sizeof(float));    // 12.3 MB
    (void)ws_size;

    k0_csr <<<1, 512, 0, stream>>>(adj, row_ptr, col_idx);
    k1_prep<<<49, 256, 0, stream>>>(W, a1, a2, Wm, p1, p2, WmT);

    // layer 1 (input = x, layout BCNT)
    k2_wh_e   <<<(BB*NN)/4, 256, 0, stream>>>(x, 0, W, p1, p2, Wh, e1, e2);
    k3_attn   <<<NROWS/4,   256, 0, stream>>>(Wh, e1, e2, row_ptr, col_idx, hpr);
    k4_out_res<<<(BB*NN)/4, 256, 0, stream>>>(hpr, Wg, bg, x, h1);

    // layer 2 (input = h1, layout BN(CT))
    k2_wh_e   <<<(BB*NN)/4, 256, 0, stream>>>(h1, 1, W, p1, p2, Wh, e1, e2);
    k3_attn   <<<NROWS/4,   256, 0, stream>>>(Wh, e1, e2, row_ptr, col_idx, hpr);
    k4_out_res<<<(BB*NN)/4, 256, 0, stream>>>(hpr, Wg, bg, x, h2);

    // final
    k5_final  <<<(BB*NN)/4, 256, 0, stream>>>(x, h1, h2, WmT, bm, out);
}

// Round 2
// 691.182 us; speedup vs baseline: 1.2581x; 1.2581x over previous
//
#include <hip/hip_runtime.h>
#include <hip/hip_bf16.h>
#include <math.h>

#define BB 8
#define CC 64
#define NN 500
#define TT 12
#define HH 4
#define FF 64
#define CT (CC*TT)      // 768
#define HF (HH*FF)      // 256
#define NROWS (BB*HH*TT*NN)  // 192000
#define DSTRIDE 128     // padded adjacency row stride (max deg ~46 << 128)

// ---------------------------------------------------------------------------
// K0: build padded adjacency list of mask = (adj + I) > 0.
// One wave per row; ballot + prefix-popcount compaction. No cross-row deps.
// ---------------------------------------------------------------------------
__global__ __launch_bounds__(256) void k0_build(const float* __restrict__ adj,
                                                int* __restrict__ deg,
                                                int* __restrict__ cols) {
    int wid  = threadIdx.x >> 6;
    int lane = threadIdx.x & 63;
    int n = blockIdx.x * 4 + wid;
    if (n >= NN) return;

    int* myc = cols + n * DSTRIDE;
    int base = 0;
    for (int m0 = 0; m0 < NN; m0 += 64) {
        int m = m0 + lane;
        bool pred = false;
        if (m < NN) {
            float v = adj[n*NN + m];
            pred = (v > 0.f) || (m == n);
        }
        unsigned long long mask = __ballot(pred);
        int pos = base + __popcll(mask & ((1ull << lane) - 1ull));
        if (pred) myc[pos] = m;
        base += __popcll(mask);
    }
    if (lane == 0) deg[n] = base;
}

// ---------------------------------------------------------------------------
// K1: prep. p1[h,c] = sum_f W[h,c,f]*a1[h,f]; p2 same with a2.
//     WmT[c*64+o] = Wm[o*192+c].
// ---------------------------------------------------------------------------
__global__ __launch_bounds__(256) void k1_prep(const float* __restrict__ W,
                                               const float* __restrict__ a1,
                                               const float* __restrict__ a2,
                                               const float* __restrict__ Wm,
                                               float* __restrict__ p1,
                                               float* __restrict__ p2,
                                               float* __restrict__ WmT) {
    int idx = blockIdx.x * 256 + threadIdx.x;
    if (idx < HH*CC) {
        int h = idx / CC, c = idx % CC;
        float s1 = 0.f, s2 = 0.f;
        for (int f = 0; f < FF; ++f) {
            float w = W[(h*CC + c)*FF + f];
            s1 += w * a1[h*FF + f];
            s2 += w * a2[h*FF + f];
        }
        p1[idx] = s1; p2[idx] = s2;
    }
    int j = idx - HH*CC;
    if (j >= 0 && j < 3*CC*CC) {   // 192*64
        int c = j >> 6, o = j & 63;
        WmT[j] = Wm[o*(3*CC) + c];
    }
}

// ---------------------------------------------------------------------------
// K2: Wh[b,h,t,n,f] = sum_c h[b,c,n,t] * W[h,c,f]   (+ e1/e2 via p1/p2)
// One wave per (b,n); lane: h = lane>>4, fb = lane&15, covers f = fb+16q.
// hin_layout: 0 = [B,C,N,T] (x), 1 = [(b*N+n)*768 + c*12 + t] (h buffers)
// ---------------------------------------------------------------------------
__global__ __launch_bounds__(256) void k2_wh_e(const float* __restrict__ hin,
                                               int hin_layout,
                                               const float* __restrict__ W,
                                               const float* __restrict__ p1,
                                               const float* __restrict__ p2,
                                               float* __restrict__ Wh,
                                               float* __restrict__ e1,
                                               float* __restrict__ e2) {
    __shared__ float hL[4][CT];
    int wid  = threadIdx.x >> 6;
    int lane = threadIdx.x & 63;
    int gidx = blockIdx.x * 4 + wid;       // (b, n)
    int b = gidx / NN, n = gidx % NN;

    if (hin_layout == 0) {
        for (int i = lane; i < CT; i += 64) {
            int c = i / TT, t = i % TT;
            hL[wid][i] = hin[((b*CC + c)*NN + n)*TT + t];
        }
    } else {
        const float* src = hin + (size_t)(b*NN + n) * CT;
        for (int i = lane; i < CT; i += 64) hL[wid][i] = src[i];
    }
    __syncthreads();

    const float* hLw = hL[wid];
    int h  = lane >> 4;
    int fb = lane & 15;

    float acc[4][TT];
    #pragma unroll
    for (int q = 0; q < 4; ++q)
        #pragma unroll
        for (int t = 0; t < TT; ++t) acc[q][t] = 0.f;

    for (int c = 0; c < CC; ++c) {
        float w0 = W[(h*CC + c)*FF + fb];
        float w1 = W[(h*CC + c)*FF + fb + 16];
        float w2 = W[(h*CC + c)*FF + fb + 32];
        float w3 = W[(h*CC + c)*FF + fb + 48];
        #pragma unroll
        for (int t = 0; t < TT; ++t) {
            float v = hLw[c*TT + t];
            acc[0][t] += v * w0;
            acc[1][t] += v * w1;
            acc[2][t] += v * w2;
            acc[3][t] += v * w3;
        }
    }
    #pragma unroll
    for (int q = 0; q < 4; ++q) {
        int f = fb + 16*q;
        #pragma unroll
        for (int t = 0; t < TT; ++t) {
            Wh[(size_t)(((b*HH + h)*TT + t)*NN + n)*FF + f] = acc[q][t];
        }
    }

    // e1/e2: lane -> (h2 = lane>>4, t2 = lane&15 if < 12)
    int t2 = lane & 15;
    if (t2 < TT) {
        int h2 = lane >> 4;
        float s1 = 0.f, s2 = 0.f;
        for (int c = 0; c < CC; ++c) {
            float v = hLw[c*TT + t2];
            s1 += v * p1[h2*CC + c];
            s2 += v * p2[h2*CC + c];
        }
        int idx = ((b*HH + h2)*TT + t2)*NN + n;
        e1[idx] = s1;
        e2[idx] = s2;
    }
}

// ---------------------------------------------------------------------------
// K3: sparse attention + PV + elu.  One wave per row r = bht*N + n.
// scores = leakyrelu(e1[n] + e2[m]); softmax over edges (shift-free: scores
// are O(1), exp cannot overflow; softmax is shift-invariant so this matches
// the reference up to fp rounding).
// ---------------------------------------------------------------------------
__global__ __launch_bounds__(256) void k3_attn(const float* __restrict__ Wh,
                                               const float* __restrict__ e1,
                                               const float* __restrict__ e2,
                                               const int* __restrict__ deg,
                                               const int* __restrict__ cols,
                                               float* __restrict__ hpr) {
    __shared__ float exw[4][DSTRIDE];
    __shared__ int   colw[4][DSTRIDE];
    int wid  = threadIdx.x >> 6;
    int lane = threadIdx.x & 63;
    int r    = blockIdx.x * 4 + wid;       // [0, NROWS)
    int n    = r % NN;
    int bht  = r / NN;

    int dg = deg[n];
    const int* ci = cols + n * DSTRIDE;
    const float* e2p = e2 + (size_t)bht * NN;
    float e1v = e1[(size_t)bht * NN + n];

    float lsum = 0.f;
    for (int i = lane; i < dg; i += 64) {
        int m = ci[i];
        float s = e1v + e2p[m];
        s = s > 0.f ? s : 0.2f * s;
        float ex = expf(s);
        exw[wid][i]  = ex;
        colw[wid][i] = m;
        lsum += ex;
    }
    #pragma unroll
    for (int d = 1; d < 64; d <<= 1) lsum += __shfl_xor(lsum, d);
    __syncthreads();

    const float* Whp = Wh + (size_t)bht * NN * FF;
    float acc = 0.f;
    for (int i = 0; i < dg; ++i) {
        float ex = exw[wid][i];
        int m    = colw[wid][i];
        acc += ex * Whp[(size_t)m * FF + lane];
    }
    acc /= lsum;
    float o = acc > 0.f ? acc : expm1f(acc);
    hpr[(size_t)((size_t)bht * NN + n) * FF + lane] = o;
}

// ---------------------------------------------------------------------------
// K4: head-mix 1x1 conv + residual.
// hnext[(b*N+n)*768 + o*12 + t] = 0.05*x[b,o,n,t] + 0.95*(bg[o] +
//      sum_k hpr[b, k>>6, t, n, k&63] * Wg[o*256+k])
// One wave per (b,n); lane: ob = lane&15, tq = lane>>4; each thread does
// o in {ob, ob+16, ob+32, ob+48}, t in {tq, tq+4, tq+8}.
// ---------------------------------------------------------------------------
__global__ __launch_bounds__(256) void k4_out_res(const float* __restrict__ hpr,
                                                  const float* __restrict__ Wg,
                                                  const float* __restrict__ bg,
                                                  const float* __restrict__ x,
                                                  float* __restrict__ hnext) {
    __shared__ float pL[4][HH*TT*FF];   // 4 x 3072 floats = 48 KB
    int wid  = threadIdx.x >> 6;
    int lane = threadIdx.x & 63;
    int gidx = blockIdx.x * 4 + wid;
    int b = gidx / NN, n = gidx % NN;

    float* P = pL[wid];
    for (int ch = 0; ch < HH*TT; ++ch) {
        P[ch*64 + lane] = hpr[(size_t)((b*HH*TT + ch)*NN + n)*FF + lane];
    }
    __syncthreads();

    int ob = lane & 15;
    int tq = lane >> 4;

    float acc[4][3];
    #pragma unroll
    for (int oi = 0; oi < 4; ++oi) {
        float bgv = bg[ob + 16*oi];
        #pragma unroll
        for (int ti = 0; ti < 3; ++ti) acc[oi][ti] = bgv;
    }

    for (int k4 = 0; k4 < 64; ++k4) {
        int h  = k4 >> 4;
        int f0 = (k4 & 15) * 4;
        float4 hv[3];
        #pragma unroll
        for (int ti = 0; ti < 3; ++ti) {
            int t = tq + 4*ti;
            hv[ti] = *(const float4*)&P[(h*TT + t)*FF + f0];
        }
        #pragma unroll
        for (int oi = 0; oi < 4; ++oi) {
            int o = ob + 16*oi;
            float4 wv = *(const float4*)&Wg[o*HF + k4*4];
            #pragma unroll
            for (int ti = 0; ti < 3; ++ti) {
                acc[oi][ti] += hv[ti].x*wv.x + hv[ti].y*wv.y
                             + hv[ti].z*wv.z + hv[ti].w*wv.w;
            }
        }
    }

    float* hout = hnext + (size_t)(b*NN + n) * CT;
    #pragma unroll
    for (int oi = 0; oi < 4; ++oi) {
        int o = ob + 16*oi;
        #pragma unroll
        for (int ti = 0; ti < 3; ++ti) {
            int t = tq + 4*ti;
            float xv = x[((b*CC + o)*NN + n)*TT + t];
            hout[o*TT + t] = 0.05f * xv + 0.95f * acc[oi][ti];
        }
    }
}

// ---------------------------------------------------------------------------
// K5: final mix. out[b,o,n,t] = bm[o] + sum_{c<192} ho[c]*Wm[o,c]
// where ho = [x | h1 | h2] along channels.  One wave per (b,n).
// ---------------------------------------------------------------------------
__global__ __launch_bounds__(256) void k5_final(const float* __restrict__ x,
                                                const float* __restrict__ h1,
                                                const float* __restrict__ h2,
                                                const float* __restrict__ WmT,
                                                const float* __restrict__ bm,
                                                float* __restrict__ out) {
    __shared__ float sL[4][3][CT];      // 36 KB
    int wid  = threadIdx.x >> 6;
    int lane = threadIdx.x & 63;
    int gidx = blockIdx.x * 4 + wid;
    int b = gidx / NN, n = gidx % NN;

    float (*S)[CT] = sL[wid];
    for (int i = lane; i < CT; i += 64) {
        int c = i / TT, t = i % TT;
        S[0][i] = x[((b*CC + c)*NN + n)*TT + t];
    }
    const float* h1p = h1 + (size_t)(b*NN + n) * CT;
    const float* h2p = h2 + (size_t)(b*NN + n) * CT;
    for (int i = lane; i < CT; i += 64) {
        S[1][i] = h1p[i];
        S[2][i] = h2p[i];
    }
    __syncthreads();

    int ob = lane & 15;
    int tq = lane >> 4;

    float acc[4][3];
    #pragma unroll
    for (int oi = 0; oi < 4; ++oi) {
        float bv = bm[ob + 16*oi];
        #pragma unroll
        for (int ti = 0; ti < 3; ++ti) acc[oi][ti] = bv;
    }

    for (int c = 0; c < CC; ++c) {
        float v0[3], v1[3], v2[3];
        #pragma unroll
        for (int ti = 0; ti < 3; ++ti) {
            int t = tq + 4*ti;
            v0[ti] = S[0][c*TT + t];
            v1[ti] = S[1][c*TT + t];
            v2[ti] = S[2][c*TT + t];
        }
        #pragma unroll
        for (int oi = 0; oi < 4; ++oi) {
            int o = ob + 16*oi;
            float w0 = WmT[(c        )*64 + o];
            float w1 = WmT[(CC  + c  )*64 + o];
            float w2 = WmT[(2*CC + c )*64 + o];
            #pragma unroll
            for (int ti = 0; ti < 3; ++ti) {
                acc[oi][ti] += v0[ti]*w0 + v1[ti]*w1 + v2[ti]*w2;
            }
        }
    }

    #pragma unroll
    for (int oi = 0; oi < 4; ++oi) {
        int o = ob + 16*oi;
        #pragma unroll
        for (int ti = 0; ti < 3; ++ti) {
            int t = tq + 4*ti;
            out[((b*CC + o)*NN + n)*TT + t] = acc[oi][ti];
        }
    }
}

// ---------------------------------------------------------------------------
extern "C" void kernel_launch(void* const* d_in, const int* in_sizes, int n_in,
                              void* d_out, int out_size, void* d_ws, size_t ws_size,
                              hipStream_t stream) {
    const float* x   = (const float*)d_in[0];
    const float* adj = (const float*)d_in[1];
    const float* W   = (const float*)d_in[2];
    const float* a1  = (const float*)d_in[3];
    const float* a2  = (const float*)d_in[4];
    const float* Wg  = (const float*)d_in[5];
    const float* bg  = (const float*)d_in[6];
    const float* Wm  = (const float*)d_in[7];
    const float* bm  = (const float*)d_in[8];
    float* out = (float*)d_out;

    char* ws = (char*)d_ws;
    size_t off = 0;
    auto alloc = [&](size_t bytes) -> void* {
        void* p = ws + off;
        off += (bytes + 255) & ~(size_t)255;
        return p;
    };

    int*   deg     = (int*)  alloc(NN * sizeof(int));
    int*   cols    = (int*)  alloc((size_t)NN * DSTRIDE * sizeof(int));
    float* p1      = (float*)alloc(HH*CC * sizeof(float));
    float* p2      = (float*)alloc(HH*CC * sizeof(float));
    float* WmT     = (float*)alloc(3*CC*CC * sizeof(float));
    float* Wh      = (float*)alloc((size_t)NROWS * FF * sizeof(float));  // 49.15 MB
    float* hpr     = (float*)alloc((size_t)NROWS * FF * sizeof(float));  // 49.15 MB
    float* e1      = (float*)alloc((size_t)NROWS * sizeof(float));
    float* e2      = (float*)alloc((size_t)NROWS * sizeof(float));
    float* h1      = (float*)alloc((size_t)BB*NN*CT * sizeof(float));    // 12.3 MB
    float* h2      = (float*)alloc((size_t)BB*NN*CT * sizeof(float));    // 12.3 MB
    (void)ws_size;

    k0_build<<<125, 256, 0, stream>>>(adj, deg, cols);
    k1_prep <<<49, 256, 0, stream>>>(W, a1, a2, Wm, p1, p2, WmT);

    // layer 1 (input = x, layout BCNT)
    k2_wh_e   <<<(BB*NN)/4, 256, 0, stream>>>(x, 0, W, p1, p2, Wh, e1, e2);
    k3_attn   <<<NROWS/4,   256, 0, stream>>>(Wh, e1, e2, deg, cols, hpr);
    k4_out_res<<<(BB*NN)/4, 256, 0, stream>>>(hpr, Wg, bg, x, h1);

    // layer 2 (input = h1, layout BN(CT))
    k2_wh_e   <<<(BB*NN)/4, 256, 0, stream>>>(h1, 1, W, p1, p2, Wh, e1, e2);
    k3_attn   <<<NROWS/4,   256, 0, stream>>>(Wh, e1, e2, deg, cols, hpr);
    k4_out_res<<<(BB*NN)/4, 256, 0, stream>>>(hpr, Wg, bg, x, h2);

    // final
    k5_final  <<<(BB*NN)/4, 256, 0, stream>>>(x, h1, h2, WmT, bm, out);
}

// Round 3
// 554.124 us; speedup vs baseline: 1.5693x; 1.2473x over previous
//
#include <hip/hip_runtime.h>
#include <hip/hip_bf16.h>
#include <math.h>

#define BB 8
#define CC 64
#define NN 500
#define TT 12
#define HH 4
#define FF 64
#define CT (CC*TT)      // 768
#define HF (HH*FF)      // 256
#define NBT (HH*TT)     // 48
#define NROWS (BB*HH*TT*NN)  // 192000
#define NNODE (BB*NN)   // 4000
#define DSTRIDE 128     // padded adjacency row stride (max deg ~46 << 128)

// ---------------------------------------------------------------------------
// K0: build padded adjacency list of mask = (adj + I) > 0.
// One wave per row; ballot + prefix-popcount compaction.
// ---------------------------------------------------------------------------
__global__ __launch_bounds__(256) void k0_build(const float* __restrict__ adj,
                                                int* __restrict__ deg,
                                                int* __restrict__ cols) {
    int wid  = threadIdx.x >> 6;
    int lane = threadIdx.x & 63;
    int n = blockIdx.x * 4 + wid;
    if (n >= NN) return;

    int* myc = cols + n * DSTRIDE;
    int base = 0;
    for (int m0 = 0; m0 < NN; m0 += 64) {
        int m = m0 + lane;
        bool pred = false;
        if (m < NN) {
            float v = adj[n*NN + m];
            pred = (v > 0.f) || (m == n);
        }
        unsigned long long mask = __ballot(pred);
        int pos = base + __popcll(mask & ((1ull << lane) - 1ull));
        if (pred) myc[pos] = m;
        base += __popcll(mask);
    }
    if (lane == 0) deg[n] = base;
}

// ---------------------------------------------------------------------------
// K6: transpose x [B,C,N,T] -> xT [(b*N+n)*768 + c*12 + t] (node-major).
// Block = (b, 16-node group); LDS tile padded 768->776 floats per node.
// ---------------------------------------------------------------------------
__global__ __launch_bounds__(256) void k6_xt(const float* __restrict__ x,
                                             float* __restrict__ xT) {
    __shared__ float tile[16*776];   // 49664 B
    int b  = blockIdx.x >> 5;        // 0..7
    int n0 = (blockIdx.x & 31) * 16; // 0,16,...,496
    for (int idx = threadIdx.x; idx < CC*16*TT; idx += 256) {
        int c   = idx / (16*TT);
        int rem = idx % (16*TT);
        int nl  = rem / TT;
        int t   = rem % TT;
        int n   = n0 + nl;
        if (n < NN)
            tile[nl*776 + c*TT + t] = x[((b*CC + c)*NN + n)*TT + t];
    }
    __syncthreads();
    for (int idx = threadIdx.x; idx < 16*CT; idx += 256) {
        int nl = idx / CT;
        int j  = idx % CT;
        int n  = n0 + nl;
        if (n < NN)
            xT[(size_t)(b*NN + n)*CT + j] = tile[nl*776 + j];
    }
}

// ---------------------------------------------------------------------------
// K1: prep. p1[h,c] = sum_f W[h,c,f]*a1[h,f]; p2 same with a2.
//     WmT[c*64+o] = Wm[o*192+c].
// ---------------------------------------------------------------------------
__global__ __launch_bounds__(256) void k1_prep(const float* __restrict__ W,
                                               const float* __restrict__ a1,
                                               const float* __restrict__ a2,
                                               const float* __restrict__ Wm,
                                               float* __restrict__ p1,
                                               float* __restrict__ p2,
                                               float* __restrict__ WmT) {
    int idx = blockIdx.x * 256 + threadIdx.x;
    if (idx < HH*CC) {
        int h = idx / CC, c = idx % CC;
        float s1 = 0.f, s2 = 0.f;
        for (int f = 0; f < FF; ++f) {
            float w = W[(h*CC + c)*FF + f];
            s1 += w * a1[h*FF + f];
            s2 += w * a2[h*FF + f];
        }
        p1[idx] = s1; p2[idx] = s2;
    }
    int j = idx - HH*CC;
    if (j >= 0 && j < 3*CC*CC) {
        int c = j >> 6, o = j & 63;
        WmT[j] = Wm[o*(3*CC) + c];
    }
}

// ---------------------------------------------------------------------------
// K2: Wh[bht][n][f] (bf16) = sum_c h[node][c,t] * W[h,c,f]; e1/e2 via p1/p2.
// Input hin is node-major [(b*N+n)*768 + c*12 + t] (xT or h buffers).
// One wave per node; lane: h = lane>>4, fb = lane&15, f = fb+16q.
// ---------------------------------------------------------------------------
__global__ __launch_bounds__(256) void k2_wh_e(const float* __restrict__ hin,
                                               const float* __restrict__ W,
                                               const float* __restrict__ p1,
                                               const float* __restrict__ p2,
                                               __hip_bfloat16* __restrict__ Wh,
                                               float* __restrict__ e1,
                                               float* __restrict__ e2) {
    __shared__ float hL[4][CT];
    int wid  = threadIdx.x >> 6;
    int lane = threadIdx.x & 63;
    int gidx = blockIdx.x * 4 + wid;       // node = b*NN + n
    int b = gidx / NN, n = gidx % NN;

    {   // coalesced float4 staging
        const float4* src = (const float4*)(hin + (size_t)gidx * CT);
        float4* dst = (float4*)hL[wid];
        for (int i = lane; i < CT/4; i += 64) dst[i] = src[i];
    }
    __syncthreads();

    const float*  hLw = hL[wid];
    const float4* h4  = (const float4*)hLw;
    int h  = lane >> 4;
    int fb = lane & 15;

    float acc[4][TT];
    #pragma unroll
    for (int q = 0; q < 4; ++q)
        #pragma unroll
        for (int t = 0; t < TT; ++t) acc[q][t] = 0.f;

    for (int c = 0; c < CC; ++c) {
        float4 v0 = h4[c*3+0], v1 = h4[c*3+1], v2 = h4[c*3+2];
        float hv[12] = {v0.x,v0.y,v0.z,v0.w, v1.x,v1.y,v1.z,v1.w,
                        v2.x,v2.y,v2.z,v2.w};
        const float* Wc = W + (h*CC + c)*FF + fb;
        float w0 = Wc[0], w1 = Wc[16], w2 = Wc[32], w3 = Wc[48];
        #pragma unroll
        for (int t = 0; t < TT; ++t) {
            acc[0][t] += hv[t]*w0;
            acc[1][t] += hv[t]*w1;
            acc[2][t] += hv[t]*w2;
            acc[3][t] += hv[t]*w3;
        }
    }
    #pragma unroll
    for (int q = 0; q < 4; ++q) {
        int f = fb + 16*q;
        #pragma unroll
        for (int t = 0; t < TT; ++t) {
            Wh[((size_t)((b*HH + h)*TT + t)*NN + n)*FF + f] =
                __float2bfloat16(acc[q][t]);
        }
    }

    // e1/e2: lane -> (h2 = lane>>4, t2 = lane&15 if < 12)
    int t2 = lane & 15;
    if (t2 < TT) {
        int h2 = lane >> 4;
        float s1 = 0.f, s2 = 0.f;
        for (int c = 0; c < CC; ++c) {
            float v = hLw[c*TT + t2];
            s1 += v * p1[h2*CC + c];
            s2 += v * p2[h2*CC + c];
        }
        int idx = ((b*HH + h2)*TT + t2)*NN + n;
        e1[idx] = s1;
        e2[idx] = s2;
    }
}

// ---------------------------------------------------------------------------
// K3: sparse attention + PV + elu.  One wave per row r = bht*N + n.
// Shift-free softmax (scores O(1), exp can't overflow; softmax shift-inv).
// hpr written NODE-MAJOR: [(b*N+n)*3072 + (h*12+t)*64 + f].
// ---------------------------------------------------------------------------
__global__ __launch_bounds__(256) void k3_attn(const __hip_bfloat16* __restrict__ Wh,
                                               const float* __restrict__ e1,
                                               const float* __restrict__ e2,
                                               const int* __restrict__ deg,
                                               const int* __restrict__ cols,
                                               float* __restrict__ hpr) {
    __shared__ float2 ew[4][DSTRIDE];      // (exp(score), col-as-float-bits)
    int wid  = threadIdx.x >> 6;
    int lane = threadIdx.x & 63;
    int r    = blockIdx.x * 4 + wid;       // [0, NROWS)
    int n    = r % NN;
    int bht  = r / NN;

    int dg = deg[n];
    const int* ci = cols + n * DSTRIDE;
    const float* e2p = e2 + (size_t)bht * NN;
    float e1v = e1[(size_t)bht * NN + n];

    float lsum = 0.f;
    for (int i = lane; i < dg; i += 64) {
        int m = ci[i];
        float s = e1v + e2p[m];
        s = s > 0.f ? s : 0.2f * s;
        float ex = __expf(s);
        ew[wid][i] = make_float2(ex, __int_as_float(m));
        lsum += ex;
    }
    #pragma unroll
    for (int d = 1; d < 64; d <<= 1) lsum += __shfl_xor(lsum, d);
    __syncthreads();

    const __hip_bfloat16* Whp = Wh + (size_t)bht * NN * FF;
    const float2* ep = ew[wid];
    float acc = 0.f;
    int i = 0;
    for (; i + 4 <= dg; i += 4) {          // 4 outstanding gathers
        float2 a0 = ep[i], a1 = ep[i+1], a2 = ep[i+2], a3 = ep[i+3];
        float v0 = __bfloat162float(Whp[(size_t)__float_as_int(a0.y)*FF + lane]);
        float v1 = __bfloat162float(Whp[(size_t)__float_as_int(a1.y)*FF + lane]);
        float v2 = __bfloat162float(Whp[(size_t)__float_as_int(a2.y)*FF + lane]);
        float v3 = __bfloat162float(Whp[(size_t)__float_as_int(a3.y)*FF + lane]);
        acc += a0.x*v0; acc += a1.x*v1; acc += a2.x*v2; acc += a3.x*v3;
    }
    for (; i < dg; ++i) {
        float2 a = ep[i];
        acc += a.x * __bfloat162float(Whp[(size_t)__float_as_int(a.y)*FF + lane]);
    }
    acc /= lsum;
    float o = acc > 0.f ? acc : expm1f(acc);
    int b = bht / NBT, ht = bht % NBT;
    hpr[((size_t)(b*NN + n)*NBT + ht)*FF + lane] = o;
}

// ---------------------------------------------------------------------------
// K4: head-mix 1x1 conv + residual.  One NODE per block (256 threads).
// P staged from node-major hpr with padded stride 68 (bank-conflict-free:
// t-neighbors land 4 banks apart).  thread -> (o = tid>>2, tg = tid&3),
// t = tg + 4*ti.  Each wave touches a 16 KB o-slice of Wg (L1-resident).
// ---------------------------------------------------------------------------
__global__ __launch_bounds__(256) void k4_out_res(const float* __restrict__ hpr,
                                                  const float* __restrict__ Wg,
                                                  const float* __restrict__ bg,
                                                  const float* __restrict__ xT,
                                                  float* __restrict__ hnext) {
    __shared__ float P[NBT*68];            // 13056 B
    int gidx = blockIdx.x;                 // node
    {
        const float4* src = (const float4*)(hpr + (size_t)gidx * (NBT*FF));
        for (int i = threadIdx.x; i < (NBT*FF)/4; i += 256) {
            float4 v = src[i];
            *(float4*)&P[(i >> 4)*68 + ((i & 15) << 2)] = v;
        }
    }
    __syncthreads();

    int o  = threadIdx.x >> 2;             // 0..63
    int tg = threadIdx.x & 3;              // t = tg, tg+4, tg+8
    float bv = bg[o];
    float acc0 = bv, acc1 = bv, acc2 = bv;
    const float4* Wg4 = (const float4*)Wg + (size_t)o * (HF/4);
    for (int kq = 0; kq < HF/4; ++kq) {
        float4 w = Wg4[kq];
        int base = (kq >> 4)*(TT*68) + ((kq & 15) << 2);
        float4 p0 = *(const float4*)&P[base + (tg    )*68];
        float4 p1 = *(const float4*)&P[base + (tg + 4)*68];
        float4 p2 = *(const float4*)&P[base + (tg + 8)*68];
        acc0 += w.x*p0.x + w.y*p0.y + w.z*p0.z + w.w*p0.w;
        acc1 += w.x*p1.x + w.y*p1.y + w.z*p1.z + w.w*p1.w;
        acc2 += w.x*p2.x + w.y*p2.y + w.z*p2.z + w.w*p2.w;
    }

    float* hout = hnext + (size_t)gidx * CT;
    const float* xp = xT + (size_t)gidx * CT;
    int j0 = o*TT + tg;
    hout[j0]     = 0.05f*xp[j0]     + 0.95f*acc0;
    hout[j0 + 4] = 0.05f*xp[j0 + 4] + 0.95f*acc1;
    hout[j0 + 8] = 0.05f*xp[j0 + 8] + 0.95f*acc2;
}

// ---------------------------------------------------------------------------
// K5: final mix. out[b,o,n,t] = bm[o] + sum_{c<192} [xT|h1|h2][c]*Wm[o,c]
// One wave per node; all three inputs node-major contiguous.
// ---------------------------------------------------------------------------
__global__ __launch_bounds__(256) void k5_final(const float* __restrict__ xT,
                                                const float* __restrict__ h1,
                                                const float* __restrict__ h2,
                                                const float* __restrict__ WmT,
                                                const float* __restrict__ bm,
                                                float* __restrict__ out) {
    __shared__ float sL[4][3][CT];         // 36 KB
    int wid  = threadIdx.x >> 6;
    int lane = threadIdx.x & 63;
    int gidx = blockIdx.x * 4 + wid;
    int b = gidx / NN, n = gidx % NN;

    {
        const float4* s0 = (const float4*)(xT + (size_t)gidx*CT);
        const float4* s1 = (const float4*)(h1 + (size_t)gidx*CT);
        const float4* s2 = (const float4*)(h2 + (size_t)gidx*CT);
        float4* d0 = (float4*)sL[wid][0];
        float4* d1 = (float4*)sL[wid][1];
        float4* d2 = (float4*)sL[wid][2];
        for (int i = lane; i < CT/4; i += 64) {
            d0[i] = s0[i]; d1[i] = s1[i]; d2[i] = s2[i];
        }
    }
    __syncthreads();

    float (*S)[CT] = sL[wid];
    int ob = lane & 15;
    int tq = lane >> 4;

    float acc[4][3];
    #pragma unroll
    for (int oi = 0; oi < 4; ++oi) {
        float bv = bm[ob + 16*oi];
        #pragma unroll
        for (int ti = 0; ti < 3; ++ti) acc[oi][ti] = bv;
    }

    for (int c = 0; c < CC; ++c) {
        float v0[3], v1[3], v2[3];
        #pragma unroll
        for (int ti = 0; ti < 3; ++ti) {
            int t = tq + 4*ti;
            v0[ti] = S[0][c*TT + t];
            v1[ti] = S[1][c*TT + t];
            v2[ti] = S[2][c*TT + t];
        }
        #pragma unroll
        for (int oi = 0; oi < 4; ++oi) {
            int o = ob + 16*oi;
            float w0 = WmT[(c       )*64 + o];
            float w1 = WmT[(CC  + c )*64 + o];
            float w2 = WmT[(2*CC + c)*64 + o];
            #pragma unroll
            for (int ti = 0; ti < 3; ++ti) {
                acc[oi][ti] += v0[ti]*w0 + v1[ti]*w1 + v2[ti]*w2;
            }
        }
    }

    #pragma unroll
    for (int oi = 0; oi < 4; ++oi) {
        int o = ob + 16*oi;
        #pragma unroll
        for (int ti = 0; ti < 3; ++ti) {
            int t = tq + 4*ti;
            out[((b*CC + o)*NN + n)*TT + t] = acc[oi][ti];
        }
    }
}

// ---------------------------------------------------------------------------
extern "C" void kernel_launch(void* const* d_in, const int* in_sizes, int n_in,
                              void* d_out, int out_size, void* d_ws, size_t ws_size,
                              hipStream_t stream) {
    const float* x   = (const float*)d_in[0];
    const float* adj = (const float*)d_in[1];
    const float* W   = (const float*)d_in[2];
    const float* a1  = (const float*)d_in[3];
    const float* a2  = (const float*)d_in[4];
    const float* Wg  = (const float*)d_in[5];
    const float* bg  = (const float*)d_in[6];
    const float* Wm  = (const float*)d_in[7];
    const float* bm  = (const float*)d_in[8];
    float* out = (float*)d_out;

    char* ws = (char*)d_ws;
    size_t off = 0;
    auto alloc = [&](size_t bytes) -> void* {
        void* p = ws + off;
        off += (bytes + 255) & ~(size_t)255;
        return p;
    };

    int*   deg  = (int*)  alloc(NN * sizeof(int));
    int*   cols = (int*)  alloc((size_t)NN * DSTRIDE * sizeof(int));
    float* p1   = (float*)alloc(HH*CC * sizeof(float));
    float* p2   = (float*)alloc(HH*CC * sizeof(float));
    float* WmT  = (float*)alloc(3*CC*CC * sizeof(float));
    float* xT   = (float*)alloc((size_t)NNODE * CT * sizeof(float));        // 12.3 MB
    __hip_bfloat16* Wh = (__hip_bfloat16*)alloc((size_t)NROWS * FF * 2);    // 24.6 MB
    float* hpr  = (float*)alloc((size_t)NNODE * NBT * FF * sizeof(float));  // 49.2 MB
    float* e1   = (float*)alloc((size_t)NROWS * sizeof(float));
    float* e2   = (float*)alloc((size_t)NROWS * sizeof(float));
    float* h1   = (float*)alloc((size_t)NNODE * CT * sizeof(float));        // 12.3 MB
    float* h2   = (float*)alloc((size_t)NNODE * CT * sizeof(float));        // 12.3 MB
    (void)ws_size;

    k0_build<<<125, 256, 0, stream>>>(adj, deg, cols);
    k6_xt   <<<256, 256, 0, stream>>>(x, xT);
    k1_prep <<<49,  256, 0, stream>>>(W, a1, a2, Wm, p1, p2, WmT);

    // layer 1
    k2_wh_e   <<<NNODE/4, 256, 0, stream>>>(xT, W, p1, p2, Wh, e1, e2);
    k3_attn   <<<NROWS/4, 256, 0, stream>>>(Wh, e1, e2, deg, cols, hpr);
    k4_out_res<<<NNODE,   256, 0, stream>>>(hpr, Wg, bg, xT, h1);

    // layer 2
    k2_wh_e   <<<NNODE/4, 256, 0, stream>>>(h1, W, p1, p2, Wh, e1, e2);
    k3_attn   <<<NROWS/4, 256, 0, stream>>>(Wh, e1, e2, deg, cols, hpr);
    k4_out_res<<<NNODE,   256, 0, stream>>>(hpr, Wg, bg, xT, h2);

    // final
    k5_final  <<<NNODE/4, 256, 0, stream>>>(xT, h1, h2, WmT, bm, out);
}

// Round 4
// 516.524 us; speedup vs baseline: 1.6836x; 1.0728x over previous
//
#include <hip/hip_runtime.h>
#include <hip/hip_bf16.h>
#include <math.h>

#define BB 8
#define CC 64
#define NN 500
#define TT 12
#define HH 4
#define FF 64
#define CT (CC*TT)      // 768
#define HF (HH*FF)      // 256
#define NBT (HH*TT)     // 48
#define NROWS (BB*HH*TT*NN)  // 192000
#define NNODE (BB*NN)   // 4000
#define DSTRIDE 128     // padded adjacency row stride (max deg ~46 << 128)

// ---------------------------------------------------------------------------
// K0: build padded adjacency list of mask = (adj + I) > 0.
// One wave per row; ballot + prefix-popcount compaction.
// ---------------------------------------------------------------------------
__global__ __launch_bounds__(256) void k0_build(const float* __restrict__ adj,
                                                int* __restrict__ deg,
                                                int* __restrict__ cols) {
    int wid  = threadIdx.x >> 6;
    int lane = threadIdx.x & 63;
    int n = blockIdx.x * 4 + wid;
    if (n >= NN) return;

    int* myc = cols + n * DSTRIDE;
    int base = 0;
    for (int m0 = 0; m0 < NN; m0 += 64) {
        int m = m0 + lane;
        bool pred = false;
        if (m < NN) {
            float v = adj[n*NN + m];
            pred = (v > 0.f) || (m == n);
        }
        unsigned long long mask = __ballot(pred);
        int pos = base + __popcll(mask & ((1ull << lane) - 1ull));
        if (pred) myc[pos] = m;
        base += __popcll(mask);
    }
    if (lane == 0) deg[n] = base;
}

// ---------------------------------------------------------------------------
// K6: transpose x [B,C,N,T] -> xT [(b*N+n)*768 + c*12 + t] (node-major).
// ---------------------------------------------------------------------------
__global__ __launch_bounds__(256) void k6_xt(const float* __restrict__ x,
                                             float* __restrict__ xT) {
    __shared__ float tile[16*776];   // 49664 B
    int b  = blockIdx.x >> 5;        // 0..7
    int n0 = (blockIdx.x & 31) * 16; // 0,16,...,496
    for (int idx = threadIdx.x; idx < CC*16*TT; idx += 256) {
        int c   = idx / (16*TT);
        int rem = idx % (16*TT);
        int nl  = rem / TT;
        int t   = rem % TT;
        int n   = n0 + nl;
        if (n < NN)
            tile[nl*776 + c*TT + t] = x[((b*CC + c)*NN + n)*TT + t];
    }
    __syncthreads();
    for (int idx = threadIdx.x; idx < 16*CT; idx += 256) {
        int nl = idx / CT;
        int j  = idx % CT;
        int n  = n0 + nl;
        if (n < NN)
            xT[(size_t)(b*NN + n)*CT + j] = tile[nl*776 + j];
    }
}

// ---------------------------------------------------------------------------
// K1: prep. p1[h,c] = sum_f W[h,c,f]*a1[h,f]; p2 same with a2.
//     WmT[c*64+o] = Wm[o*192+c].
// ---------------------------------------------------------------------------
__global__ __launch_bounds__(256) void k1_prep(const float* __restrict__ W,
                                               const float* __restrict__ a1,
                                               const float* __restrict__ a2,
                                               const float* __restrict__ Wm,
                                               float* __restrict__ p1,
                                               float* __restrict__ p2,
                                               float* __restrict__ WmT) {
    int idx = blockIdx.x * 256 + threadIdx.x;
    if (idx < HH*CC) {
        int h = idx / CC, c = idx % CC;
        float s1 = 0.f, s2 = 0.f;
        for (int f = 0; f < FF; ++f) {
            float w = W[(h*CC + c)*FF + f];
            s1 += w * a1[h*FF + f];
            s2 += w * a2[h*FF + f];
        }
        p1[idx] = s1; p2[idx] = s2;
    }
    int j = idx - HH*CC;
    if (j >= 0 && j < 3*CC*CC) {
        int c = j >> 6, o = j & 63;
        WmT[j] = Wm[o*(3*CC) + c];
    }
}

// ---------------------------------------------------------------------------
// K2: Wh[bht][n][f] (bf16) = sum_c h[node][c,t] * W[h,c,f]; e1/e2 via p1/p2.
// ---------------------------------------------------------------------------
__global__ __launch_bounds__(256) void k2_wh_e(const float* __restrict__ hin,
                                               const float* __restrict__ W,
                                               const float* __restrict__ p1,
                                               const float* __restrict__ p2,
                                               __hip_bfloat16* __restrict__ Wh,
                                               float* __restrict__ e1,
                                               float* __restrict__ e2) {
    __shared__ float hL[4][CT];
    int wid  = threadIdx.x >> 6;
    int lane = threadIdx.x & 63;
    int gidx = blockIdx.x * 4 + wid;       // node = b*NN + n
    int b = gidx / NN, n = gidx % NN;

    {   // coalesced float4 staging
        const float4* src = (const float4*)(hin + (size_t)gidx * CT);
        float4* dst = (float4*)hL[wid];
        for (int i = lane; i < CT/4; i += 64) dst[i] = src[i];
    }
    __syncthreads();

    const float*  hLw = hL[wid];
    const float4* h4  = (const float4*)hLw;
    int h  = lane >> 4;
    int fb = lane & 15;

    float acc[4][TT];
    #pragma unroll
    for (int q = 0; q < 4; ++q)
        #pragma unroll
        for (int t = 0; t < TT; ++t) acc[q][t] = 0.f;

    for (int c = 0; c < CC; ++c) {
        float4 v0 = h4[c*3+0], v1 = h4[c*3+1], v2 = h4[c*3+2];
        float hv[12] = {v0.x,v0.y,v0.z,v0.w, v1.x,v1.y,v1.z,v1.w,
                        v2.x,v2.y,v2.z,v2.w};
        const float* Wc = W + (h*CC + c)*FF + fb;
        float w0 = Wc[0], w1 = Wc[16], w2 = Wc[32], w3 = Wc[48];
        #pragma unroll
        for (int t = 0; t < TT; ++t) {
            acc[0][t] += hv[t]*w0;
            acc[1][t] += hv[t]*w1;
            acc[2][t] += hv[t]*w2;
            acc[3][t] += hv[t]*w3;
        }
    }
    #pragma unroll
    for (int q = 0; q < 4; ++q) {
        int f = fb + 16*q;
        #pragma unroll
        for (int t = 0; t < TT; ++t) {
            Wh[((size_t)((b*HH + h)*TT + t)*NN + n)*FF + f] =
                __float2bfloat16(acc[q][t]);
        }
    }

    int t2 = lane & 15;
    if (t2 < TT) {
        int h2 = lane >> 4;
        float s1 = 0.f, s2 = 0.f;
        for (int c = 0; c < CC; ++c) {
            float v = hLw[c*TT + t2];
            s1 += v * p1[h2*CC + c];
            s2 += v * p2[h2*CC + c];
        }
        int idx = ((b*HH + h2)*TT + t2)*NN + n;
        e1[idx] = s1;
        e2[idx] = s2;
    }
}

// ---------------------------------------------------------------------------
// K3: sparse attention + PV + elu.  One wave per row r = bht*N + n.
// Phase 2 processes 4 edges/iteration: lane-group g = lane>>4 handles edge
// i+g; each lane loads dwordx2 (4 bf16 f-values) -> one global_load fetches
// 4 full Wh rows (512 B/wave).  Edge list padded to multiple of 4 with
// (ex=0, m=0) records (exact no-op).  Butterfly xor{16,32} sums the 4
// groups; lanes 0-15 normalize + elu + float4 store.
// hpr written NODE-MAJOR: [(b*N+n)*3072 + (h*12+t)*64 + f].
// ---------------------------------------------------------------------------
__global__ __launch_bounds__(256) void k3_attn(const __hip_bfloat16* __restrict__ Wh,
                                               const float* __restrict__ e1,
                                               const float* __restrict__ e2,
                                               const int* __restrict__ deg,
                                               const int* __restrict__ cols,
                                               float* __restrict__ hpr) {
    __shared__ float2 ew[4][DSTRIDE];      // (exp(score), col-as-float-bits)
    int wid  = threadIdx.x >> 6;
    int lane = threadIdx.x & 63;
    int r    = blockIdx.x * 4 + wid;       // [0, NROWS)
    int n    = r % NN;
    int bht  = r / NN;

    int dg  = deg[n];
    int dgp = (dg + 3) & ~3;
    const int* ci = cols + n * DSTRIDE;
    const float* e2p = e2 + (size_t)bht * NN;
    float e1v = e1[(size_t)bht * NN + n];

    float lsum = 0.f;
    for (int i = lane; i < dg; i += 64) {
        int m = ci[i];
        float s = e1v + e2p[m];
        s = s > 0.f ? s : 0.2f * s;
        float ex = __expf(s);
        ew[wid][i] = make_float2(ex, __int_as_float(m));
        lsum += ex;
    }
    if (lane < dgp - dg)                   // pad: weight-0 gathers of row 0
        ew[wid][dg + lane] = make_float2(0.f, __int_as_float(0));
    #pragma unroll
    for (int d = 1; d < 64; d <<= 1) lsum += __shfl_xor(lsum, d);
    __syncthreads();

    const __hip_bfloat16* Whp = Wh + (size_t)bht * NN * FF;
    const float2* ep = ew[wid];
    int g  = lane >> 4;                    // edge subgroup 0..3
    int fl = lane & 15;                    // f quad: f = fl*4 + j

    float ax = 0.f, ay = 0.f, az = 0.f, aw = 0.f;
    for (int i = 0; i < dgp; i += 4) {
        float2 a = ep[i + g];
        int m = __float_as_int(a.y);
        const uint2* wp = (const uint2*)((const char*)Whp +
                            ((size_t)m << 7) + (fl << 3));
        uint2 w = *wp;
        float v0 = __int_as_float(w.x << 16);
        float v1 = __int_as_float(w.x & 0xffff0000u);
        float v2 = __int_as_float(w.y << 16);
        float v3 = __int_as_float(w.y & 0xffff0000u);
        ax += a.x * v0;
        ay += a.x * v1;
        az += a.x * v2;
        aw += a.x * v3;
    }
    // sum the 4 edge-subgroups (lanes l, l^16, l^32, l^48)
    ax += __shfl_xor(ax, 16); ay += __shfl_xor(ay, 16);
    az += __shfl_xor(az, 16); aw += __shfl_xor(aw, 16);
    ax += __shfl_xor(ax, 32); ay += __shfl_xor(ay, 32);
    az += __shfl_xor(az, 32); aw += __shfl_xor(aw, 32);

    if (lane < 16) {
        float inv = 1.0f / lsum;
        float4 rv;
        rv.x = ax * inv; rv.y = ay * inv; rv.z = az * inv; rv.w = aw * inv;
        rv.x = rv.x > 0.f ? rv.x : __expf(rv.x) - 1.f;
        rv.y = rv.y > 0.f ? rv.y : __expf(rv.y) - 1.f;
        rv.z = rv.z > 0.f ? rv.z : __expf(rv.z) - 1.f;
        rv.w = rv.w > 0.f ? rv.w : __expf(rv.w) - 1.f;
        int b = bht / NBT, ht = bht % NBT;
        float4* dst = (float4*)&hpr[((size_t)(b*NN + n)*NBT + ht)*FF] + fl;
        *dst = rv;
    }
}

// ---------------------------------------------------------------------------
// K4: head-mix 1x1 conv + residual.  One NODE per block (256 threads).
// ---------------------------------------------------------------------------
__global__ __launch_bounds__(256) void k4_out_res(const float* __restrict__ hpr,
                                                  const float* __restrict__ Wg,
                                                  const float* __restrict__ bg,
                                                  const float* __restrict__ xT,
                                                  float* __restrict__ hnext) {
    __shared__ float P[NBT*68];            // 13056 B
    int gidx = blockIdx.x;                 // node
    {
        const float4* src = (const float4*)(hpr + (size_t)gidx * (NBT*FF));
        for (int i = threadIdx.x; i < (NBT*FF)/4; i += 256) {
            float4 v = src[i];
            *(float4*)&P[(i >> 4)*68 + ((i & 15) << 2)] = v;
        }
    }
    __syncthreads();

    int o  = threadIdx.x >> 2;             // 0..63
    int tg = threadIdx.x & 3;              // t = tg, tg+4, tg+8
    float bv = bg[o];
    float acc0 = bv, acc1 = bv, acc2 = bv;
    const float4* Wg4 = (const float4*)Wg + (size_t)o * (HF/4);
    for (int kq = 0; kq < HF/4; ++kq) {
        float4 w = Wg4[kq];
        int base = (kq >> 4)*(TT*68) + ((kq & 15) << 2);
        float4 p0 = *(const float4*)&P[base + (tg    )*68];
        float4 p1 = *(const float4*)&P[base + (tg + 4)*68];
        float4 p2 = *(const float4*)&P[base + (tg + 8)*68];
        acc0 += w.x*p0.x + w.y*p0.y + w.z*p0.z + w.w*p0.w;
        acc1 += w.x*p1.x + w.y*p1.y + w.z*p1.z + w.w*p1.w;
        acc2 += w.x*p2.x + w.y*p2.y + w.z*p2.z + w.w*p2.w;
    }

    float* hout = hnext + (size_t)gidx * CT;
    const float* xp = xT + (size_t)gidx * CT;
    int j0 = o*TT + tg;
    hout[j0]     = 0.05f*xp[j0]     + 0.95f*acc0;
    hout[j0 + 4] = 0.05f*xp[j0 + 4] + 0.95f*acc1;
    hout[j0 + 8] = 0.05f*xp[j0 + 8] + 0.95f*acc2;
}

// ---------------------------------------------------------------------------
// K5: final mix. out[b,o,n,t] = bm[o] + sum_{c<192} [xT|h1|h2][c]*Wm[o,c]
// ---------------------------------------------------------------------------
__global__ __launch_bounds__(256) void k5_final(const float* __restrict__ xT,
                                                const float* __restrict__ h1,
                                                const float* __restrict__ h2,
                                                const float* __restrict__ WmT,
                                                const float* __restrict__ bm,
                                                float* __restrict__ out) {
    __shared__ float sL[4][3][CT];         // 36 KB
    int wid  = threadIdx.x >> 6;
    int lane = threadIdx.x & 63;
    int gidx = blockIdx.x * 4 + wid;
    int b = gidx / NN, n = gidx % NN;

    {
        const float4* s0 = (const float4*)(xT + (size_t)gidx*CT);
        const float4* s1 = (const float4*)(h1 + (size_t)gidx*CT);
        const float4* s2 = (const float4*)(h2 + (size_t)gidx*CT);
        float4* d0 = (float4*)sL[wid][0];
        float4* d1 = (float4*)sL[wid][1];
        float4* d2 = (float4*)sL[wid][2];
        for (int i = lane; i < CT/4; i += 64) {
            d0[i] = s0[i]; d1[i] = s1[i]; d2[i] = s2[i];
        }
    }
    __syncthreads();

    float (*S)[CT] = sL[wid];
    int ob = lane & 15;
    int tq = lane >> 4;

    float acc[4][3];
    #pragma unroll
    for (int oi = 0; oi < 4; ++oi) {
        float bv = bm[ob + 16*oi];
        #pragma unroll
        for (int ti = 0; ti < 3; ++ti) acc[oi][ti] = bv;
    }

    for (int c = 0; c < CC; ++c) {
        float v0[3], v1[3], v2[3];
        #pragma unroll
        for (int ti = 0; ti < 3; ++ti) {
            int t = tq + 4*ti;
            v0[ti] = S[0][c*TT + t];
            v1[ti] = S[1][c*TT + t];
            v2[ti] = S[2][c*TT + t];
        }
        #pragma unroll
        for (int oi = 0; oi < 4; ++oi) {
            int o = ob + 16*oi;
            float w0 = WmT[(c       )*64 + o];
            float w1 = WmT[(CC  + c )*64 + o];
            float w2 = WmT[(2*CC + c)*64 + o];
            #pragma unroll
            for (int ti = 0; ti < 3; ++ti) {
                acc[oi][ti] += v0[ti]*w0 + v1[ti]*w1 + v2[ti]*w2;
            }
        }
    }

    #pragma unroll
    for (int oi = 0; oi < 4; ++oi) {
        int o = ob + 16*oi;
        #pragma unroll
        for (int ti = 0; ti < 3; ++ti) {
            int t = tq + 4*ti;
            out[((b*CC + o)*NN + n)*TT + t] = acc[oi][ti];
        }
    }
}

// ---------------------------------------------------------------------------
extern "C" void kernel_launch(void* const* d_in, const int* in_sizes, int n_in,
                              void* d_out, int out_size, void* d_ws, size_t ws_size,
                              hipStream_t stream) {
    const float* x   = (const float*)d_in[0];
    const float* adj = (const float*)d_in[1];
    const float* W   = (const float*)d_in[2];
    const float* a1  = (const float*)d_in[3];
    const float* a2  = (const float*)d_in[4];
    const float* Wg  = (const float*)d_in[5];
    const float* bg  = (const float*)d_in[6];
    const float* Wm  = (const float*)d_in[7];
    const float* bm  = (const float*)d_in[8];
    float* out = (float*)d_out;

    char* ws = (char*)d_ws;
    size_t off = 0;
    auto alloc = [&](size_t bytes) -> void* {
        void* p = ws + off;
        off += (bytes + 255) & ~(size_t)255;
        return p;
    };

    int*   deg  = (int*)  alloc(NN * sizeof(int));
    int*   cols = (int*)  alloc((size_t)NN * DSTRIDE * sizeof(int));
    float* p1   = (float*)alloc(HH*CC * sizeof(float));
    float* p2   = (float*)alloc(HH*CC * sizeof(float));
    float* WmT  = (float*)alloc(3*CC*CC * sizeof(float));
    float* xT   = (float*)alloc((size_t)NNODE * CT * sizeof(float));        // 12.3 MB
    __hip_bfloat16* Wh = (__hip_bfloat16*)alloc((size_t)NROWS * FF * 2);    // 24.6 MB
    float* hpr  = (float*)alloc((size_t)NNODE * NBT * FF * sizeof(float));  // 49.2 MB
    float* e1   = (float*)alloc((size_t)NROWS * sizeof(float));
    float* e2   = (float*)alloc((size_t)NROWS * sizeof(float));
    float* h1   = (float*)alloc((size_t)NNODE * CT * sizeof(float));        // 12.3 MB
    float* h2   = (float*)alloc((size_t)NNODE * CT * sizeof(float));        // 12.3 MB
    (void)ws_size;

    k0_build<<<125, 256, 0, stream>>>(adj, deg, cols);
    k6_xt   <<<256, 256, 0, stream>>>(x, xT);
    k1_prep <<<49,  256, 0, stream>>>(W, a1, a2, Wm, p1, p2, WmT);

    // layer 1
    k2_wh_e   <<<NNODE/4, 256, 0, stream>>>(xT, W, p1, p2, Wh, e1, e2);
    k3_attn   <<<NROWS/4, 256, 0, stream>>>(Wh, e1, e2, deg, cols, hpr);
    k4_out_res<<<NNODE,   256, 0, stream>>>(hpr, Wg, bg, xT, h1);

    // layer 2
    k2_wh_e   <<<NNODE/4, 256, 0, stream>>>(h1, W, p1, p2, Wh, e1, e2);
    k3_attn   <<<NROWS/4, 256, 0, stream>>>(Wh, e1, e2, deg, cols, hpr);
    k4_out_res<<<NNODE,   256, 0, stream>>>(hpr, Wg, bg, xT, h2);

    // final
    k5_final  <<<NNODE/4, 256, 0, stream>>>(xT, h1, h2, WmT, bm, out);
}